// Round 1
// baseline (1044.778 us; speedup 1.0000x reference)
//
#include <hip/hip_runtime.h>
#include <math.h>

#define FF 256
#define HH 64

__device__ __forceinline__ float readlane_f(float v, int l) {
    return __uint_as_float((unsigned)__builtin_amdgcn_readlane((int)__float_as_uint(v), l));
}
__device__ __forceinline__ float gelu_f(float x) {
    return 0.5f * x * (1.0f + erff(x * 0.70710678118654752f));
}
__device__ __forceinline__ float wave_sum(float d) {
    #pragma unroll
    for (int off = 32; off; off >>= 1) d += __shfl_xor(d, off, 64);
    return d;
}

// ---------------- CSR build ----------------
__global__ __launch_bounds__(256) void k_degree(const int* __restrict__ dst,
        int* __restrict__ deg, int E) {
    int e = blockIdx.x * 256 + threadIdx.x;
    if (e < E) atomicAdd(&deg[dst[e]], 1);
}

__global__ __launch_bounds__(256) void k_scan1(const int* __restrict__ deg,
        int* __restrict__ out, int* __restrict__ bsums, int n) {
    __shared__ int lds[256];
    int t = threadIdx.x;
    int base = blockIdx.x * 1024 + t * 4;
    int v0 = (base     < n) ? deg[base]     : 0;
    int v1 = (base + 1 < n) ? deg[base + 1] : 0;
    int v2 = (base + 2 < n) ? deg[base + 2] : 0;
    int v3 = (base + 3 < n) ? deg[base + 3] : 0;
    int s = v0 + v1 + v2 + v3;
    int val = s;
    lds[t] = val;
    __syncthreads();
    #pragma unroll
    for (int off = 1; off < 256; off <<= 1) {
        int tmp = (t >= off) ? lds[t - off] : 0;
        __syncthreads();
        val += tmp;
        lds[t] = val;
        __syncthreads();
    }
    if (t == 255) bsums[blockIdx.x] = val;
    int excl = val - s;
    if (base     < n) out[base]     = excl;
    if (base + 1 < n) out[base + 1] = excl + v0;
    if (base + 2 < n) out[base + 2] = excl + v0 + v1;
    if (base + 3 < n) out[base + 3] = excl + v0 + v1 + v2;
}

__global__ __launch_bounds__(256) void k_scan2(const int* __restrict__ bsums,
        int* __restrict__ boffs, int nb) {
    __shared__ int lds[256];
    int t = threadIdx.x;
    int s = (t < nb) ? bsums[t] : 0;
    int val = s;
    lds[t] = val;
    __syncthreads();
    #pragma unroll
    for (int off = 1; off < 256; off <<= 1) {
        int tmp = (t >= off) ? lds[t - off] : 0;
        __syncthreads();
        val += tmp;
        lds[t] = val;
        __syncthreads();
    }
    if (t < nb) boffs[t] = val - s;
}

__global__ __launch_bounds__(256) void k_scan3(int* __restrict__ rowptr,
        const int* __restrict__ boffs, int n, int E) {
    int i = blockIdx.x * 256 + threadIdx.x;
    if (i < n) rowptr[i] += boffs[i >> 10];
    if (i == n) rowptr[n] = E;
}

__global__ __launch_bounds__(256) void k_fill(const int* __restrict__ src,
        const int* __restrict__ dst, const int* __restrict__ rowptr,
        int* __restrict__ cursor, int* __restrict__ eid, int* __restrict__ esrc, int E) {
    int e = blockIdx.x * 256 + threadIdx.x;
    if (e < E) {
        int d = dst[e];
        int pos = rowptr[d] + atomicAdd(&cursor[d], 1);
        eid[pos]  = e;
        esrc[pos] = src[e];
    }
}

// ---------------- proj GEMM + gelu ----------------
__global__ __launch_bounds__(256) void k_proj(const float* __restrict__ x,
        const float* __restrict__ W, const float* __restrict__ b,
        float* __restrict__ h, int n) {
    __shared__ float Wl[FF * HH];
    for (int i = threadIdx.x; i < FF * HH / 4; i += 256)
        reinterpret_cast<float4*>(Wl)[i] = reinterpret_cast<const float4*>(W)[i];
    __syncthreads();
    int lane = threadIdx.x & 63;
    int wid  = blockIdx.x * 4 + (threadIdx.x >> 6);
    int nw   = gridDim.x * 4;
    float bias = b[lane];
    for (int row = wid; row < n; row += nw) {
        float4 xv = reinterpret_cast<const float4*>(x + (size_t)row * FF)[lane];
        float acc = bias;
        #pragma unroll 8
        for (int k4 = 0; k4 < 64; ++k4) {
            float a0 = readlane_f(xv.x, k4);
            float a1 = readlane_f(xv.y, k4);
            float a2 = readlane_f(xv.z, k4);
            float a3 = readlane_f(xv.w, k4);
            const float* wp = Wl + k4 * 4 * HH + lane;
            acc += a0 * wp[0];
            acc += a1 * wp[HH];
            acc += a2 * wp[2 * HH];
            acc += a3 * wp[3 * HH];
        }
        h[(size_t)row * HH + lane] = gelu_f(acc);
    }
}

// ---------------- fused QKV GEMM ----------------
__global__ __launch_bounds__(256) void k_qkv(const float* __restrict__ h,
        const float* __restrict__ Wq, const float* __restrict__ Wk, const float* __restrict__ Wv,
        float* __restrict__ q, float* __restrict__ k, float* __restrict__ v, int n) {
    __shared__ float Wl[3 * HH * HH];
    for (int i = threadIdx.x; i < HH * HH / 4; i += 256) {
        reinterpret_cast<float4*>(Wl)[i]               = reinterpret_cast<const float4*>(Wq)[i];
        reinterpret_cast<float4*>(Wl + HH * HH)[i]     = reinterpret_cast<const float4*>(Wk)[i];
        reinterpret_cast<float4*>(Wl + 2 * HH * HH)[i] = reinterpret_cast<const float4*>(Wv)[i];
    }
    __syncthreads();
    int lane = threadIdx.x & 63;
    int wid  = blockIdx.x * 4 + (threadIdx.x >> 6);
    int nw   = gridDim.x * 4;
    for (int row = wid; row < n; row += nw) {
        float hv = h[(size_t)row * HH + lane];
        float aq = 0.f, ak = 0.f, av = 0.f;
        #pragma unroll 8
        for (int kk = 0; kk < HH; ++kk) {
            float hb = readlane_f(hv, kk);
            aq += hb * Wl[kk * HH + lane];
            ak += hb * Wl[HH * HH + kk * HH + lane];
            av += hb * Wl[2 * HH * HH + kk * HH + lane];
        }
        q[(size_t)row * HH + lane] = aq;
        k[(size_t)row * HH + lane] = ak;
        v[(size_t)row * HH + lane] = av;
    }
}

// ---------------- GAT edge phase: one wave per destination node ----------------
template<bool LAST>
__global__ __launch_bounds__(256) void k_edge(
        const float* __restrict__ q, const float* __restrict__ karr,
        const float* __restrict__ varr,
        const int* __restrict__ rowptr, const int* __restrict__ eid,
        const int* __restrict__ esrc,
        float* __restrict__ alpha_csr,
        float* __restrict__ attn_out,
        float* __restrict__ hout,
        float* __restrict__ signals,
        const float* __restrict__ Wsig, const float* __restrict__ bsig,
        int n) {
    int node = blockIdx.x * 4 + (threadIdx.x >> 6);
    if (node >= n) return;
    int lane  = threadIdx.x & 63;
    int start = rowptr[node], end = rowptr[node + 1];
    int deg   = end - start;
    float qv  = q[(size_t)node * HH + lane];
    float m   = -INFINITY;

    // pass 1: scores -> relu -> alpha (CSR order), running max
    for (int c = 0; c < deg; c += 64) {
        int p  = start + c + lane;
        int sl = (p < end) ? esrc[p] : 0;
        float areg = 0.f;
        int cnt = min(64, deg - c);
        for (int jj = 0; jj < cnt; ++jj) {
            int sv   = __builtin_amdgcn_readlane(sl, jj);
            float kv = karr[(size_t)sv * HH + lane];
            float d  = wave_sum(qv * kv);
            float alpha = fmaxf(d * 0.125f, 0.f);
            m = fmaxf(m, alpha);
            areg = (lane == jj) ? alpha : areg;
        }
        if (p < end) alpha_csr[p] = areg;
    }

    // pass 2: denom
    float s = 0.f;
    for (int p = start + lane; p < end; p += 64) s += expf(alpha_csr[p] - m);
    s = wave_sum(s);
    float inv = 1.0f / (s + 1e-16f);

    // pass 3: a -> attn out (orig edge order) + weighted aggregation of v
    float acc = 0.f;
    for (int c = 0; c < deg; c += 64) {
        int p = start + c + lane;
        bool valid = p < end;
        int sl   = valid ? esrc[p] : 0;
        int el   = valid ? eid[p]  : 0;
        float al = valid ? alpha_csr[p] : 0.f;
        float a  = expf(al - m) * inv;
        if (valid) attn_out[el] = a;
        int cnt = min(64, deg - c);
        for (int jj = 0; jj < cnt; ++jj) {
            float av = readlane_f(a, jj);
            int   sv = __builtin_amdgcn_readlane(sl, jj);
            acc += av * varr[(size_t)sv * HH + lane];
        }
    }

    if (!LAST) {
        hout[(size_t)node * HH + lane] = gelu_f(acc);
    } else {
        float t = wave_sum(acc * Wsig[lane]);
        if (lane == 0) signals[node] = t + bsig[0];
    }
}

extern "C" void kernel_launch(void* const* d_in, const int* in_sizes, int n_in,
                              void* d_out, int out_size, void* d_ws, size_t ws_size,
                              hipStream_t stream) {
    const float* x   = (const float*)d_in[0];
    const int*   ei  = (const int*)  d_in[1];
    const float* Wp  = (const float*)d_in[2];
    const float* bp  = (const float*)d_in[3];
    const float* Wq1 = (const float*)d_in[4];
    const float* Wk1 = (const float*)d_in[5];
    const float* Wv1 = (const float*)d_in[6];
    const float* Wq2 = (const float*)d_in[7];
    const float* Wk2 = (const float*)d_in[8];
    const float* Wv2 = (const float*)d_in[9];
    const float* Wsg = (const float*)d_in[10];
    const float* bsg = (const float*)d_in[11];

    const int N = in_sizes[0] / FF;
    const int E = in_sizes[1] / 2;
    const int* src = ei;
    const int* dst = ei + E;

    // workspace carve-up
    char* ws = (char*)d_ws;
    size_t off = 0;
    auto alloc = [&](size_t bytes) -> void* {
        void* p = ws + off;
        off += (bytes + 255) & ~(size_t)255;
        return p;
    };
    float* q     = (float*)alloc((size_t)N * HH * 4);
    float* k     = (float*)alloc((size_t)N * HH * 4);
    float* v     = (float*)alloc((size_t)N * HH * 4);
    float* h     = (float*)alloc((size_t)N * HH * 4);
    float* alpha = (float*)alloc((size_t)E * 4);
    int* eid     = (int*)alloc((size_t)E * 4);
    int* esrc    = (int*)alloc((size_t)E * 4);
    int* degcur  = (int*)alloc((size_t)2 * N * 4);   // deg | cursor
    int* deg     = degcur;
    int* cursor  = degcur + N;
    int* rowptr  = (int*)alloc((size_t)(N + 1) * 4);
    int* bsums   = (int*)alloc(256 * 4);
    int* boffs   = (int*)alloc(256 * 4);

    float* out     = (float*)d_out;
    float* signals = out;
    float* attn1   = out + N;
    float* attn2   = out + N + E;

    // CSR build
    hipMemsetAsync(degcur, 0, (size_t)2 * N * 4, stream);
    k_degree<<<(E + 255) / 256, 256, 0, stream>>>(dst, deg, E);
    int nb = (N + 1023) / 1024;
    k_scan1<<<nb, 256, 0, stream>>>(deg, rowptr, bsums, N);
    k_scan2<<<1, 256, 0, stream>>>(bsums, boffs, nb);
    k_scan3<<<(N + 1 + 255) / 256, 256, 0, stream>>>(rowptr, boffs, N, E);
    k_fill<<<(E + 255) / 256, 256, 0, stream>>>(src, dst, rowptr, cursor, eid, esrc, E);

    // layer 0: projection + gelu
    k_proj<<<2048, 256, 0, stream>>>(x, Wp, bp, h, N);

    // layer 1
    k_qkv<<<1536, 256, 0, stream>>>(h, Wq1, Wk1, Wv1, q, k, v, N);
    k_edge<false><<<(N + 3) / 4, 256, 0, stream>>>(q, k, v, rowptr, eid, esrc,
            alpha, attn1, h, nullptr, nullptr, nullptr, N);

    // layer 2 (+ fused signal head)
    k_qkv<<<1536, 256, 0, stream>>>(h, Wq2, Wk2, Wv2, q, k, v, N);
    k_edge<true><<<(N + 3) / 4, 256, 0, stream>>>(q, k, v, rowptr, eid, esrc,
            alpha, attn2, nullptr, signals, Wsg, bsg, N);
}

// Round 2
// 746.511 us; speedup vs baseline: 1.3995x; 1.3995x over previous
//
#include <hip/hip_runtime.h>
#include <math.h>

#define FF 256
#define HH 64

__device__ __forceinline__ float gelu_f(float x) {
    return 0.5f * x * (1.0f + erff(x * 0.70710678118654752f));
}

// ---------------- CSR build ----------------
__global__ __launch_bounds__(256) void k_degree(const int* __restrict__ dst,
        int* __restrict__ deg, int E) {
    int e = blockIdx.x * 256 + threadIdx.x;
    if (e < E) atomicAdd(&deg[dst[e]], 1);
}

__global__ __launch_bounds__(256) void k_scan1(const int* __restrict__ deg,
        int* __restrict__ out, int* __restrict__ bsums, int n) {
    __shared__ int lds[256];
    int t = threadIdx.x;
    int base = blockIdx.x * 1024 + t * 4;
    int v0 = (base     < n) ? deg[base]     : 0;
    int v1 = (base + 1 < n) ? deg[base + 1] : 0;
    int v2 = (base + 2 < n) ? deg[base + 2] : 0;
    int v3 = (base + 3 < n) ? deg[base + 3] : 0;
    int s = v0 + v1 + v2 + v3;
    int val = s;
    lds[t] = val;
    __syncthreads();
    #pragma unroll
    for (int off = 1; off < 256; off <<= 1) {
        int tmp = (t >= off) ? lds[t - off] : 0;
        __syncthreads();
        val += tmp;
        lds[t] = val;
        __syncthreads();
    }
    if (t == 255) bsums[blockIdx.x] = val;
    int excl = val - s;
    if (base     < n) out[base]     = excl;
    if (base + 1 < n) out[base + 1] = excl + v0;
    if (base + 2 < n) out[base + 2] = excl + v0 + v1;
    if (base + 3 < n) out[base + 3] = excl + v0 + v1 + v2;
}

__global__ __launch_bounds__(256) void k_scan2(const int* __restrict__ bsums,
        int* __restrict__ boffs, int nb) {
    __shared__ int lds[256];
    int t = threadIdx.x;
    int s = (t < nb) ? bsums[t] : 0;
    int val = s;
    lds[t] = val;
    __syncthreads();
    #pragma unroll
    for (int off = 1; off < 256; off <<= 1) {
        int tmp = (t >= off) ? lds[t - off] : 0;
        __syncthreads();
        val += tmp;
        lds[t] = val;
        __syncthreads();
    }
    if (t < nb) boffs[t] = val - s;
}

__global__ __launch_bounds__(256) void k_scan3(int* __restrict__ rowptr,
        const int* __restrict__ boffs, int n, int E) {
    int i = blockIdx.x * 256 + threadIdx.x;
    if (i < n) rowptr[i] += boffs[i >> 10];
    if (i == n) rowptr[n] = E;
}

__global__ __launch_bounds__(256) void k_fill(const int* __restrict__ src,
        const int* __restrict__ dst, const int* __restrict__ rowptr,
        int* __restrict__ cursor, int* __restrict__ eid, int* __restrict__ esrc, int E) {
    int e = blockIdx.x * 256 + threadIdx.x;
    if (e < E) {
        int d = dst[e];
        int pos = rowptr[d] + atomicAdd(&cursor[d], 1);
        eid[pos]  = e;
        esrc[pos] = src[e];
    }
}

// ---------------- proj GEMM + gelu: 8 rows/wave, scalar activation broadcast --------
__global__ __launch_bounds__(256) void k_proj(const float* __restrict__ x,
        const float* __restrict__ W, const float* __restrict__ b,
        float* __restrict__ h, int n) {
    __shared__ float Wl[FF * HH];
    for (int i = threadIdx.x; i < FF * HH / 4; i += 256)
        reinterpret_cast<float4*>(Wl)[i] = reinterpret_cast<const float4*>(W)[i];
    __syncthreads();
    int lane  = threadIdx.x & 63;
    int wid   = blockIdx.x * 4 + (threadIdx.x >> 6);
    int wid_u = __builtin_amdgcn_readfirstlane(wid);
    int r0    = wid_u * 8;
    if (r0 >= n) return;
    const float* xb[8];
    #pragma unroll
    for (int r = 0; r < 8; ++r) {
        int rr = r0 + r;
        xb[r] = x + (size_t)(rr < n ? rr : n - 1) * FF;
    }
    float acc[8] = {0.f, 0.f, 0.f, 0.f, 0.f, 0.f, 0.f, 0.f};
    #pragma unroll 8
    for (int kk = 0; kk < FF; ++kk) {
        float w = Wl[kk * HH + lane];
        #pragma unroll
        for (int r = 0; r < 8; ++r)
            acc[r] = fmaf(xb[r][kk], w, acc[r]);
    }
    float bias = b[lane];
    #pragma unroll
    for (int r = 0; r < 8; ++r)
        if (r0 + r < n)
            h[(size_t)(r0 + r) * HH + lane] = gelu_f(acc[r] + bias);
}

// ---------------- fused QKV GEMM: 4 rows/wave ----------------
__global__ __launch_bounds__(256) void k_qkv(const float* __restrict__ h,
        const float* __restrict__ Wq, const float* __restrict__ Wk, const float* __restrict__ Wv,
        float* __restrict__ q, float* __restrict__ k, float* __restrict__ v, int n) {
    __shared__ float Wl[3 * HH * HH];
    for (int i = threadIdx.x; i < HH * HH / 4; i += 256) {
        reinterpret_cast<float4*>(Wl)[i]               = reinterpret_cast<const float4*>(Wq)[i];
        reinterpret_cast<float4*>(Wl + HH * HH)[i]     = reinterpret_cast<const float4*>(Wk)[i];
        reinterpret_cast<float4*>(Wl + 2 * HH * HH)[i] = reinterpret_cast<const float4*>(Wv)[i];
    }
    __syncthreads();
    int lane  = threadIdx.x & 63;
    int wid   = blockIdx.x * 4 + (threadIdx.x >> 6);
    int wid_u = __builtin_amdgcn_readfirstlane(wid);
    int r0    = wid_u * 4;
    if (r0 >= n) return;
    const float* hb[4];
    #pragma unroll
    for (int r = 0; r < 4; ++r) {
        int rr = r0 + r;
        hb[r] = h + (size_t)(rr < n ? rr : n - 1) * HH;
    }
    float aq[4] = {0.f, 0.f, 0.f, 0.f};
    float ak[4] = {0.f, 0.f, 0.f, 0.f};
    float av[4] = {0.f, 0.f, 0.f, 0.f};
    #pragma unroll 8
    for (int kk = 0; kk < HH; ++kk) {
        float wq = Wl[kk * HH + lane];
        float wk = Wl[HH * HH + kk * HH + lane];
        float wv = Wl[2 * HH * HH + kk * HH + lane];
        #pragma unroll
        for (int r = 0; r < 4; ++r) {
            float hh = hb[r][kk];
            aq[r] = fmaf(hh, wq, aq[r]);
            ak[r] = fmaf(hh, wk, ak[r]);
            av[r] = fmaf(hh, wv, av[r]);
        }
    }
    #pragma unroll
    for (int r = 0; r < 4; ++r) {
        if (r0 + r < n) {
            q[(size_t)(r0 + r) * HH + lane] = aq[r];
            k[(size_t)(r0 + r) * HH + lane] = ak[r];
            v[(size_t)(r0 + r) * HH + lane] = av[r];
        }
    }
}

// ---------------- GAT edge phase: one wave/node, 16 lanes/edge, single gather pass --
template<bool LAST>
__global__ __launch_bounds__(256) void k_edge(
        const float* __restrict__ q, const float* __restrict__ karr,
        const float* __restrict__ varr,
        const int* __restrict__ rowptr, const int* __restrict__ eid,
        const int* __restrict__ esrc,
        float* __restrict__ ecsr,
        float* __restrict__ attn_out,
        float* __restrict__ hout,
        float* __restrict__ signals,
        const float* __restrict__ Wsig, const float* __restrict__ bsig,
        int n) {
    int node = blockIdx.x * 4 + (threadIdx.x >> 6);
    if (node >= n) return;
    int lane = threadIdx.x & 63;
    int li = lane & 15, g = lane >> 4;
    int start = rowptr[node], end = rowptr[node + 1];
    int deg = end - start;
    float4 qv = *reinterpret_cast<const float4*>(q + (size_t)node * HH + li * 4);
    int p0 = start + lane;
    int el = (p0 < end) ? esrc[p0] : 0;      // first 64 source indices in registers

    float4 acc = {0.f, 0.f, 0.f, 0.f};
    float s = 0.f;
    for (int c = 0; c < deg; c += 4) {
        int idx = c + g;
        bool valid = idx < deg;
        int sv;
        if (c < 64) sv = __shfl(el, idx);                 // wave-uniform branch
        else        sv = valid ? esrc[start + idx] : 0;
        const float4 kv = *reinterpret_cast<const float4*>(karr + (size_t)sv * HH + li * 4);
        const float4 vv = *reinterpret_cast<const float4*>(varr + (size_t)sv * HH + li * 4);
        float d = qv.x * kv.x + qv.y * kv.y + qv.z * kv.z + qv.w * kv.w;
        d += __shfl_xor(d, 1);
        d += __shfl_xor(d, 2);
        d += __shfl_xor(d, 4);
        d += __shfl_xor(d, 8);
        float e = valid ? __expf(fmaxf(d * 0.125f, 0.f)) : 0.f;
        s += e;
        if (valid && li == 0) ecsr[start + idx] = e;
        acc.x = fmaf(e, vv.x, acc.x);
        acc.y = fmaf(e, vv.y, acc.y);
        acc.z = fmaf(e, vv.z, acc.z);
        acc.w = fmaf(e, vv.w, acc.w);
    }
    // combine the 4 groups
    s += __shfl_xor(s, 16); s += __shfl_xor(s, 32);
    acc.x += __shfl_xor(acc.x, 16); acc.x += __shfl_xor(acc.x, 32);
    acc.y += __shfl_xor(acc.y, 16); acc.y += __shfl_xor(acc.y, 32);
    acc.z += __shfl_xor(acc.z, 16); acc.z += __shfl_xor(acc.z, 32);
    acc.w += __shfl_xor(acc.w, 16); acc.w += __shfl_xor(acc.w, 32);
    float inv = 1.0f / (s + 1e-16f);

    if (!LAST) {
        if (g == 0) {
            float4 o;
            o.x = gelu_f(acc.x * inv);
            o.y = gelu_f(acc.y * inv);
            o.z = gelu_f(acc.z * inv);
            o.w = gelu_f(acc.w * inv);
            *reinterpret_cast<float4*>(hout + (size_t)node * HH + li * 4) = o;
        }
    } else {
        float4 w4 = *reinterpret_cast<const float4*>(Wsig + li * 4);
        float t = (acc.x * w4.x + acc.y * w4.y + acc.z * w4.z + acc.w * w4.w) * inv;
        t += __shfl_xor(t, 1);
        t += __shfl_xor(t, 2);
        t += __shfl_xor(t, 4);
        t += __shfl_xor(t, 8);
        if (lane == 0) signals[node] = t + bsig[0];
    }
    // attention coefficients in original edge order
    for (int p = p0; p < end; p += 64)
        attn_out[eid[p]] = ecsr[p] * inv;
}

extern "C" void kernel_launch(void* const* d_in, const int* in_sizes, int n_in,
                              void* d_out, int out_size, void* d_ws, size_t ws_size,
                              hipStream_t stream) {
    const float* x   = (const float*)d_in[0];
    const int*   ei  = (const int*)  d_in[1];
    const float* Wp  = (const float*)d_in[2];
    const float* bp  = (const float*)d_in[3];
    const float* Wq1 = (const float*)d_in[4];
    const float* Wk1 = (const float*)d_in[5];
    const float* Wv1 = (const float*)d_in[6];
    const float* Wq2 = (const float*)d_in[7];
    const float* Wk2 = (const float*)d_in[8];
    const float* Wv2 = (const float*)d_in[9];
    const float* Wsg = (const float*)d_in[10];
    const float* bsg = (const float*)d_in[11];

    const int N = in_sizes[0] / FF;
    const int E = in_sizes[1] / 2;
    const int* src = ei;
    const int* dst = ei + E;

    char* ws = (char*)d_ws;
    size_t off = 0;
    auto alloc = [&](size_t bytes) -> void* {
        void* p = ws + off;
        off += (bytes + 255) & ~(size_t)255;
        return p;
    };
    float* q     = (float*)alloc((size_t)N * HH * 4);
    float* k     = (float*)alloc((size_t)N * HH * 4);
    float* v     = (float*)alloc((size_t)N * HH * 4);
    float* h     = (float*)alloc((size_t)N * HH * 4);
    float* ecsr  = (float*)alloc((size_t)E * 4);
    int* eid     = (int*)alloc((size_t)E * 4);
    int* esrc    = (int*)alloc((size_t)E * 4);
    int* degcur  = (int*)alloc((size_t)2 * N * 4);
    int* deg     = degcur;
    int* cursor  = degcur + N;
    int* rowptr  = (int*)alloc((size_t)(N + 1) * 4);
    int* bsums   = (int*)alloc(256 * 4);
    int* boffs   = (int*)alloc(256 * 4);

    float* out     = (float*)d_out;
    float* signals = out;
    float* attn1   = out + N;
    float* attn2   = out + N + E;

    // CSR build
    hipMemsetAsync(degcur, 0, (size_t)2 * N * 4, stream);
    k_degree<<<(E + 255) / 256, 256, 0, stream>>>(dst, deg, E);
    int nb = (N + 1023) / 1024;
    k_scan1<<<nb, 256, 0, stream>>>(deg, rowptr, bsums, N);
    k_scan2<<<1, 256, 0, stream>>>(bsums, boffs, nb);
    k_scan3<<<(N + 1 + 255) / 256, 256, 0, stream>>>(rowptr, boffs, N, E);
    k_fill<<<(E + 255) / 256, 256, 0, stream>>>(src, dst, rowptr, cursor, eid, esrc, E);

    // layer 0: projection + gelu   (8 rows/wave, 4 waves/block)
    int projBlocks = ((N + 7) / 8 + 3) / 4;
    k_proj<<<projBlocks, 256, 0, stream>>>(x, Wp, bp, h, N);

    int qkvBlocks = ((N + 3) / 4 + 3) / 4;
    // layer 1
    k_qkv<<<qkvBlocks, 256, 0, stream>>>(h, Wq1, Wk1, Wv1, q, k, v, N);
    k_edge<false><<<(N + 3) / 4, 256, 0, stream>>>(q, k, v, rowptr, eid, esrc,
            ecsr, attn1, h, nullptr, nullptr, nullptr, N);

    // layer 2 (+ fused signal head)
    k_qkv<<<qkvBlocks, 256, 0, stream>>>(h, Wq2, Wk2, Wv2, q, k, v, N);
    k_edge<true><<<(N + 3) / 4, 256, 0, stream>>>(q, k, v, rowptr, eid, esrc,
            ecsr, attn2, nullptr, signals, Wsg, bsg, N);
}

// Round 3
// 672.264 us; speedup vs baseline: 1.5541x; 1.1104x over previous
//
#include <hip/hip_runtime.h>
#include <math.h>

#define FF 256
#define HH 64

__device__ __forceinline__ float gelu_f(float x) {
    return 0.5f * x * (1.0f + erff(x * 0.70710678118654752f));
}

// ---------------- CSR build ----------------
__global__ __launch_bounds__(256) void k_degree(const int* __restrict__ dst,
        int* __restrict__ deg, int E) {
    int e = blockIdx.x * 256 + threadIdx.x;
    if (e < E) atomicAdd(&deg[dst[e]], 1);
}

__global__ __launch_bounds__(256) void k_scan1(const int* __restrict__ deg,
        int* __restrict__ out, int* __restrict__ bsums, int n) {
    __shared__ int lds[256];
    int t = threadIdx.x;
    int base = blockIdx.x * 1024 + t * 4;
    int v0 = (base     < n) ? deg[base]     : 0;
    int v1 = (base + 1 < n) ? deg[base + 1] : 0;
    int v2 = (base + 2 < n) ? deg[base + 2] : 0;
    int v3 = (base + 3 < n) ? deg[base + 3] : 0;
    int s = v0 + v1 + v2 + v3;
    int val = s;
    lds[t] = val;
    __syncthreads();
    #pragma unroll
    for (int off = 1; off < 256; off <<= 1) {
        int tmp = (t >= off) ? lds[t - off] : 0;
        __syncthreads();
        val += tmp;
        lds[t] = val;
        __syncthreads();
    }
    if (t == 255) bsums[blockIdx.x] = val;
    int excl = val - s;
    if (base     < n) out[base]     = excl;
    if (base + 1 < n) out[base + 1] = excl + v0;
    if (base + 2 < n) out[base + 2] = excl + v0 + v1;
    if (base + 3 < n) out[base + 3] = excl + v0 + v1 + v2;
}

__global__ __launch_bounds__(256) void k_scan2(const int* __restrict__ bsums,
        int* __restrict__ boffs, int nb) {
    __shared__ int lds[256];
    int t = threadIdx.x;
    int s = (t < nb) ? bsums[t] : 0;
    int val = s;
    lds[t] = val;
    __syncthreads();
    #pragma unroll
    for (int off = 1; off < 256; off <<= 1) {
        int tmp = (t >= off) ? lds[t - off] : 0;
        __syncthreads();
        val += tmp;
        lds[t] = val;
        __syncthreads();
    }
    if (t < nb) boffs[t] = val - s;
}

__global__ __launch_bounds__(256) void k_scan3(int* __restrict__ rowptr,
        const int* __restrict__ boffs, int n, int E) {
    int i = blockIdx.x * 256 + threadIdx.x;
    if (i < n) rowptr[i] += boffs[i >> 10];
    if (i == n) rowptr[n] = E;
}

__global__ __launch_bounds__(256) void k_fill(const int* __restrict__ src,
        const int* __restrict__ dst, const int* __restrict__ rowptr,
        int* __restrict__ cursor, int* __restrict__ eid, int* __restrict__ esrc, int E) {
    int e = blockIdx.x * 256 + threadIdx.x;
    if (e < E) {
        int d = dst[e];
        int pos = rowptr[d] + atomicAdd(&cursor[d], 1);
        eid[pos]  = e;
        esrc[pos] = src[e];
    }
}

// ---------------- proj GEMM + gelu ----------------
// lane = output column; 16 rows per wave. W via vector loads (vmcnt, L1-resident);
// x via scalar s_loads (lgkmcnt, uniform base + imm offsets). No LDS.
__global__ __launch_bounds__(256) void k_proj(const float* __restrict__ x,
        const float* __restrict__ W, const float* __restrict__ b,
        float* __restrict__ h, int n) {
    int lane = threadIdx.x & 63;
    int wid  = __builtin_amdgcn_readfirstlane(blockIdx.x * 4 + (threadIdx.x >> 6));
    int r0   = wid * 16;
    if (r0 >= n) return;
    const float* xb = x + (size_t)r0 * FF;
    float acc[16];
    #pragma unroll
    for (int r = 0; r < 16; ++r) acc[r] = 0.f;
    #pragma unroll 4
    for (int kk = 0; kk < FF; ++kk) {
        float w = W[kk * HH + lane];
        #pragma unroll
        for (int r = 0; r < 16; ++r)
            acc[r] = fmaf(xb[(size_t)r * FF + kk], w, acc[r]);
    }
    float bias = b[lane];
    #pragma unroll
    for (int r = 0; r < 16; ++r)
        h[(size_t)(r0 + r) * HH + lane] = gelu_f(acc[r] + bias);
}

// ---------------- fused QKV GEMM: same structure, K=64, 3 outputs ----------------
__global__ __launch_bounds__(256) void k_qkv(const float* __restrict__ h,
        const float* __restrict__ Wq, const float* __restrict__ Wk, const float* __restrict__ Wv,
        float* __restrict__ q, float* __restrict__ k, float* __restrict__ v, int n) {
    int lane = threadIdx.x & 63;
    int wid  = __builtin_amdgcn_readfirstlane(blockIdx.x * 4 + (threadIdx.x >> 6));
    int r0   = wid * 16;
    if (r0 >= n) return;
    const float* hb = h + (size_t)r0 * HH;
    float aq[16], ak[16], av[16];
    #pragma unroll
    for (int r = 0; r < 16; ++r) { aq[r] = 0.f; ak[r] = 0.f; av[r] = 0.f; }
    #pragma unroll 4
    for (int kk = 0; kk < HH; ++kk) {
        float wq = Wq[kk * HH + lane];
        float wk = Wk[kk * HH + lane];
        float wv = Wv[kk * HH + lane];
        #pragma unroll
        for (int r = 0; r < 16; ++r) {
            float hh = hb[(size_t)r * HH + kk];
            aq[r] = fmaf(hh, wq, aq[r]);
            ak[r] = fmaf(hh, wk, ak[r]);
            av[r] = fmaf(hh, wv, av[r]);
        }
    }
    #pragma unroll
    for (int r = 0; r < 16; ++r) {
        q[(size_t)(r0 + r) * HH + lane] = aq[r];
        k[(size_t)(r0 + r) * HH + lane] = ak[r];
        v[(size_t)(r0 + r) * HH + lane] = av[r];
    }
}

// ---------------- GAT edge phase: one wave/node, 16 lanes/edge, single gather pass --
template<bool LAST>
__global__ __launch_bounds__(256) void k_edge(
        const float* __restrict__ q, const float* __restrict__ karr,
        const float* __restrict__ varr,
        const int* __restrict__ rowptr, const int* __restrict__ eid,
        const int* __restrict__ esrc,
        float* __restrict__ ecsr,
        float* __restrict__ attn_out,
        float* __restrict__ hout,
        float* __restrict__ signals,
        const float* __restrict__ Wsig, const float* __restrict__ bsig,
        int n) {
    int node = blockIdx.x * 4 + (threadIdx.x >> 6);
    if (node >= n) return;
    int lane = threadIdx.x & 63;
    int li = lane & 15, g = lane >> 4;
    int start = rowptr[node], end = rowptr[node + 1];
    int deg = end - start;
    float4 qv = *reinterpret_cast<const float4*>(q + (size_t)node * HH + li * 4);
    int p0 = start + lane;
    int el = (p0 < end) ? esrc[p0] : 0;      // first 64 source indices in registers

    float4 acc = {0.f, 0.f, 0.f, 0.f};
    float s = 0.f;
    for (int c = 0; c < deg; c += 4) {
        int idx = c + g;
        bool valid = idx < deg;
        int sv;
        if (c < 64) sv = __shfl(el, idx);                 // wave-uniform branch
        else        sv = valid ? esrc[start + idx] : 0;
        const float4 kv = *reinterpret_cast<const float4*>(karr + (size_t)sv * HH + li * 4);
        const float4 vv = *reinterpret_cast<const float4*>(varr + (size_t)sv * HH + li * 4);
        float d = qv.x * kv.x + qv.y * kv.y + qv.z * kv.z + qv.w * kv.w;
        d += __shfl_xor(d, 1);
        d += __shfl_xor(d, 2);
        d += __shfl_xor(d, 4);
        d += __shfl_xor(d, 8);
        float e = valid ? __expf(fmaxf(d * 0.125f, 0.f)) : 0.f;
        s += e;
        if (valid && li == 0) ecsr[start + idx] = e;
        acc.x = fmaf(e, vv.x, acc.x);
        acc.y = fmaf(e, vv.y, acc.y);
        acc.z = fmaf(e, vv.z, acc.z);
        acc.w = fmaf(e, vv.w, acc.w);
    }
    // combine the 4 groups
    s += __shfl_xor(s, 16); s += __shfl_xor(s, 32);
    acc.x += __shfl_xor(acc.x, 16); acc.x += __shfl_xor(acc.x, 32);
    acc.y += __shfl_xor(acc.y, 16); acc.y += __shfl_xor(acc.y, 32);
    acc.z += __shfl_xor(acc.z, 16); acc.z += __shfl_xor(acc.z, 32);
    acc.w += __shfl_xor(acc.w, 16); acc.w += __shfl_xor(acc.w, 32);
    float inv = 1.0f / (s + 1e-16f);

    if (!LAST) {
        if (g == 0) {
            float4 o;
            o.x = gelu_f(acc.x * inv);
            o.y = gelu_f(acc.y * inv);
            o.z = gelu_f(acc.z * inv);
            o.w = gelu_f(acc.w * inv);
            *reinterpret_cast<float4*>(hout + (size_t)node * HH + li * 4) = o;
        }
    } else {
        float4 w4 = *reinterpret_cast<const float4*>(Wsig + li * 4);
        float t = (acc.x * w4.x + acc.y * w4.y + acc.z * w4.z + acc.w * w4.w) * inv;
        t += __shfl_xor(t, 1);
        t += __shfl_xor(t, 2);
        t += __shfl_xor(t, 4);
        t += __shfl_xor(t, 8);
        if (lane == 0) signals[node] = t + bsig[0];
    }
    // attention coefficients in original edge order
    for (int p = p0; p < end; p += 64)
        attn_out[eid[p]] = ecsr[p] * inv;
}

extern "C" void kernel_launch(void* const* d_in, const int* in_sizes, int n_in,
                              void* d_out, int out_size, void* d_ws, size_t ws_size,
                              hipStream_t stream) {
    const float* x   = (const float*)d_in[0];
    const int*   ei  = (const int*)  d_in[1];
    const float* Wp  = (const float*)d_in[2];
    const float* bp  = (const float*)d_in[3];
    const float* Wq1 = (const float*)d_in[4];
    const float* Wk1 = (const float*)d_in[5];
    const float* Wv1 = (const float*)d_in[6];
    const float* Wq2 = (const float*)d_in[7];
    const float* Wk2 = (const float*)d_in[8];
    const float* Wv2 = (const float*)d_in[9];
    const float* Wsg = (const float*)d_in[10];
    const float* bsg = (const float*)d_in[11];

    const int N = in_sizes[0] / FF;
    const int E = in_sizes[1] / 2;
    const int* src = ei;
    const int* dst = ei + E;

    char* ws = (char*)d_ws;
    size_t off = 0;
    auto alloc = [&](size_t bytes) -> void* {
        void* p = ws + off;
        off += (bytes + 255) & ~(size_t)255;
        return p;
    };
    float* q     = (float*)alloc((size_t)N * HH * 4);
    float* k     = (float*)alloc((size_t)N * HH * 4);
    float* v     = (float*)alloc((size_t)N * HH * 4);
    float* h     = (float*)alloc((size_t)N * HH * 4);
    float* ecsr  = (float*)alloc((size_t)E * 4);
    int* eid     = (int*)alloc((size_t)E * 4);
    int* esrc    = (int*)alloc((size_t)E * 4);
    int* degcur  = (int*)alloc((size_t)2 * N * 4);
    int* deg     = degcur;
    int* cursor  = degcur + N;
    int* rowptr  = (int*)alloc((size_t)(N + 1) * 4);
    int* bsums   = (int*)alloc(256 * 4);
    int* boffs   = (int*)alloc(256 * 4);

    float* out     = (float*)d_out;
    float* signals = out;
    float* attn1   = out + N;
    float* attn2   = out + N + E;

    // CSR build
    hipMemsetAsync(degcur, 0, (size_t)2 * N * 4, stream);
    k_degree<<<(E + 255) / 256, 256, 0, stream>>>(dst, deg, E);
    int nb = (N + 1023) / 1024;
    k_scan1<<<nb, 256, 0, stream>>>(deg, rowptr, bsums, N);
    k_scan2<<<1, 256, 0, stream>>>(bsums, boffs, nb);
    k_scan3<<<(N + 1 + 255) / 256, 256, 0, stream>>>(rowptr, boffs, N, E);
    k_fill<<<(E + 255) / 256, 256, 0, stream>>>(src, dst, rowptr, cursor, eid, esrc, E);

    // GEMM grids: 16 rows/wave, 4 waves/block
    int gemmBlocks = ((N + 15) / 16 + 3) / 4;

    // layer 0: projection + gelu
    k_proj<<<gemmBlocks, 256, 0, stream>>>(x, Wp, bp, h, N);

    // layer 1
    k_qkv<<<gemmBlocks, 256, 0, stream>>>(h, Wq1, Wk1, Wv1, q, k, v, N);
    k_edge<false><<<(N + 3) / 4, 256, 0, stream>>>(q, k, v, rowptr, eid, esrc,
            ecsr, attn1, h, nullptr, nullptr, nullptr, N);

    // layer 2 (+ fused signal head)
    k_qkv<<<gemmBlocks, 256, 0, stream>>>(h, Wq2, Wk2, Wv2, q, k, v, N);
    k_edge<true><<<(N + 3) / 4, 256, 0, stream>>>(q, k, v, rowptr, eid, esrc,
            ecsr, attn2, nullptr, signals, Wsg, bsg, N);
}

// Round 4
// 558.951 us; speedup vs baseline: 1.8692x; 1.2027x over previous
//
#include <hip/hip_runtime.h>
#include <math.h>

#define FF 256
#define HH 64

typedef __attribute__((ext_vector_type(8))) short short8;
typedef __attribute__((ext_vector_type(4))) float f32x4;

__device__ __forceinline__ float gelu_f(float x) {
    return 0.5f * x * (1.0f + erff(x * 0.70710678118654752f));
}

// split f into bf16 hi + bf16 lo (RNE), manual integer rounding
__device__ __forceinline__ void bf16split(float f, short& hi, short& lo) {
    unsigned u = __float_as_uint(f);
    unsigned r = u + 0x7FFFu + ((u >> 16) & 1u);
    hi = (short)(r >> 16);
    float fh = __uint_as_float(r & 0xFFFF0000u);
    float fl = f - fh;
    unsigned u2 = __float_as_uint(fl);
    unsigned r2 = u2 + 0x7FFFu + ((u2 >> 16) & 1u);
    lo = (short)(r2 >> 16);
}

// ---- W fragment tables in workspace (bf16 hi/lo, fragment-ordered) ----
// proj  : pairs fid in [0,16384)   hi at wf[fid],            lo at wf[16384+fid]
// mat m : base = 32768 + m*8192;   hi at base+fid (fid<4096), lo at base+4096+fid
// fid = ((s*4 + ct)*64 + lane)*8 + j ; k = s*32 + (lane>>4)*8 + j ; col = ct*16 + (lane&15)
__global__ __launch_bounds__(256) void k_wprep(
        const float* __restrict__ Wp,
        const float* __restrict__ Wq1, const float* __restrict__ Wk1, const float* __restrict__ Wv1,
        const float* __restrict__ Wq2, const float* __restrict__ Wk2, const float* __restrict__ Wv2,
        short* __restrict__ wf) {
    int total = 16384 + 6 * 4096;
    for (int gid = blockIdx.x * 256 + threadIdx.x; gid < total; gid += gridDim.x * 256) {
        const float* W;
        int fid, hibase, lobase;
        if (gid < 16384) {
            W = Wp; fid = gid; hibase = 0; lobase = 16384;
        } else {
            int t = gid - 16384;
            int m = t >> 12;
            fid = t & 4095;
            switch (m) {
                case 0: W = Wq1; break;
                case 1: W = Wk1; break;
                case 2: W = Wv1; break;
                case 3: W = Wq2; break;
                case 4: W = Wk2; break;
                default: W = Wv2; break;
            }
            hibase = 32768 + m * 8192;
            lobase = hibase + 4096;
        }
        int j    = fid & 7;
        int lane = (fid >> 3) & 63;
        int ct   = (fid >> 9) & 3;
        int s    = fid >> 11;
        int k    = s * 32 + (lane >> 4) * 8 + j;
        int col  = ct * 16 + (lane & 15);
        short hi, lo;
        bf16split(W[k * HH + col], hi, lo);
        wf[hibase + fid] = hi;
        wf[lobase + fid] = lo;
    }
}

// ---------------- CSR build ----------------
__global__ __launch_bounds__(256) void k_degree(const int* __restrict__ dst,
        int* __restrict__ deg, int E) {
    int e = blockIdx.x * 256 + threadIdx.x;
    if (e < E) atomicAdd(&deg[dst[e]], 1);
}

__global__ __launch_bounds__(256) void k_scan1(const int* __restrict__ deg,
        int* __restrict__ out, int* __restrict__ bsums, int n) {
    __shared__ int lds[256];
    int t = threadIdx.x;
    int base = blockIdx.x * 1024 + t * 4;
    int v0 = (base     < n) ? deg[base]     : 0;
    int v1 = (base + 1 < n) ? deg[base + 1] : 0;
    int v2 = (base + 2 < n) ? deg[base + 2] : 0;
    int v3 = (base + 3 < n) ? deg[base + 3] : 0;
    int s = v0 + v1 + v2 + v3;
    int val = s;
    lds[t] = val;
    __syncthreads();
    #pragma unroll
    for (int off = 1; off < 256; off <<= 1) {
        int tmp = (t >= off) ? lds[t - off] : 0;
        __syncthreads();
        val += tmp;
        lds[t] = val;
        __syncthreads();
    }
    if (t == 255) bsums[blockIdx.x] = val;
    int excl = val - s;
    if (base     < n) out[base]     = excl;
    if (base + 1 < n) out[base + 1] = excl + v0;
    if (base + 2 < n) out[base + 2] = excl + v0 + v1;
    if (base + 3 < n) out[base + 3] = excl + v0 + v1 + v2;
}

__global__ __launch_bounds__(256) void k_scan2(const int* __restrict__ bsums,
        int* __restrict__ boffs, int nb) {
    __shared__ int lds[256];
    int t = threadIdx.x;
    int s = (t < nb) ? bsums[t] : 0;
    int val = s;
    lds[t] = val;
    __syncthreads();
    #pragma unroll
    for (int off = 1; off < 256; off <<= 1) {
        int tmp = (t >= off) ? lds[t - off] : 0;
        __syncthreads();
        val += tmp;
        lds[t] = val;
        __syncthreads();
    }
    if (t < nb) boffs[t] = val - s;
}

__global__ __launch_bounds__(256) void k_scan3(int* __restrict__ rowptr,
        const int* __restrict__ boffs, int n, int E) {
    int i = blockIdx.x * 256 + threadIdx.x;
    if (i < n) rowptr[i] += boffs[i >> 10];
    if (i == n) rowptr[n] = E;
}

__global__ __launch_bounds__(256) void k_fill(const int* __restrict__ src,
        const int* __restrict__ dst, const int* __restrict__ rowptr,
        int* __restrict__ cursor, int* __restrict__ eid, int* __restrict__ esrc, int E) {
    int e = blockIdx.x * 256 + threadIdx.x;
    if (e < E) {
        int d = dst[e];
        int pos = rowptr[d] + atomicAdd(&cursor[d], 1);
        eid[pos]  = e;
        esrc[pos] = src[e];
    }
}

// ---------------- proj GEMM + gelu via MFMA (split-bf16, 3 terms) ----------------
// block = 4 waves; wave handles 16 rows x 64 cols; K = 256 in 8 steps of 32.
__global__ __launch_bounds__(256) void k_proj(const float* __restrict__ x,
        const short* __restrict__ wf, const float* __restrict__ b,
        float* __restrict__ h, int n) {
    int lane = threadIdx.x & 63;
    int w    = threadIdx.x >> 6;
    int m    = lane & 15, g = lane >> 4;
    int rowc = min(blockIdx.x * 64 + w * 16 + m, n - 1);
    const float* xrow = x + (size_t)rowc * FF + g * 8;
    const short* wlo = wf + 16384;
    f32x4 acc[4];
    #pragma unroll
    for (int ct = 0; ct < 4; ++ct) acc[ct] = (f32x4){0.f, 0.f, 0.f, 0.f};
    #pragma unroll
    for (int s = 0; s < 8; ++s) {
        float4 a0 = *reinterpret_cast<const float4*>(xrow + s * 32);
        float4 a1 = *reinterpret_cast<const float4*>(xrow + s * 32 + 4);
        float av[8] = {a0.x, a0.y, a0.z, a0.w, a1.x, a1.y, a1.z, a1.w};
        short8 ah, al;
        #pragma unroll
        for (int j = 0; j < 8; ++j) { short hi, lo; bf16split(av[j], hi, lo); ah[j] = hi; al[j] = lo; }
        #pragma unroll
        for (int ct = 0; ct < 4; ++ct) {
            int fo = ((s * 4 + ct) * 64 + lane) * 8;
            short8 bh = *reinterpret_cast<const short8*>(wf + fo);
            short8 bl = *reinterpret_cast<const short8*>(wlo + fo);
            acc[ct] = __builtin_amdgcn_mfma_f32_16x16x32_bf16(ah, bh, acc[ct], 0, 0, 0);
            acc[ct] = __builtin_amdgcn_mfma_f32_16x16x32_bf16(al, bh, acc[ct], 0, 0, 0);
            acc[ct] = __builtin_amdgcn_mfma_f32_16x16x32_bf16(ah, bl, acc[ct], 0, 0, 0);
        }
    }
    int orow0 = blockIdx.x * 64 + w * 16 + g * 4;
    #pragma unroll
    for (int ct = 0; ct < 4; ++ct) {
        int col = ct * 16 + m;
        float bias = b[col];
        #pragma unroll
        for (int r = 0; r < 4; ++r) {
            int row = orow0 + r;
            if (row < n) h[(size_t)row * HH + col] = gelu_f(acc[ct][r] + bias);
        }
    }
}

// ---------------- fused QKV GEMM via MFMA ----------------
__global__ __launch_bounds__(256) void k_qkv(const float* __restrict__ hsrc,
        const short* __restrict__ wfq, const short* __restrict__ wfk, const short* __restrict__ wfv,
        float* __restrict__ q, float* __restrict__ k, float* __restrict__ v, int n) {
    int lane = threadIdx.x & 63;
    int w    = threadIdx.x >> 6;
    int m    = lane & 15, g = lane >> 4;
    int rowc = min(blockIdx.x * 64 + w * 16 + m, n - 1);
    const float* hrow = hsrc + (size_t)rowc * HH + g * 8;
    f32x4 aq[4], ak[4], av_[4];
    #pragma unroll
    for (int ct = 0; ct < 4; ++ct) {
        aq[ct] = (f32x4){0.f, 0.f, 0.f, 0.f};
        ak[ct] = (f32x4){0.f, 0.f, 0.f, 0.f};
        av_[ct] = (f32x4){0.f, 0.f, 0.f, 0.f};
    }
    #pragma unroll
    for (int s = 0; s < 2; ++s) {
        float4 a0 = *reinterpret_cast<const float4*>(hrow + s * 32);
        float4 a1 = *reinterpret_cast<const float4*>(hrow + s * 32 + 4);
        float avv[8] = {a0.x, a0.y, a0.z, a0.w, a1.x, a1.y, a1.z, a1.w};
        short8 ah, al;
        #pragma unroll
        for (int j = 0; j < 8; ++j) { short hi, lo; bf16split(avv[j], hi, lo); ah[j] = hi; al[j] = lo; }
        #pragma unroll
        for (int ct = 0; ct < 4; ++ct) {
            int fo = ((s * 4 + ct) * 64 + lane) * 8;
            short8 qh = *reinterpret_cast<const short8*>(wfq + fo);
            short8 ql = *reinterpret_cast<const short8*>(wfq + 4096 + fo);
            short8 kh = *reinterpret_cast<const short8*>(wfk + fo);
            short8 kl = *reinterpret_cast<const short8*>(wfk + 4096 + fo);
            short8 vh = *reinterpret_cast<const short8*>(wfv + fo);
            short8 vl = *reinterpret_cast<const short8*>(wfv + 4096 + fo);
            aq[ct] = __builtin_amdgcn_mfma_f32_16x16x32_bf16(ah, qh, aq[ct], 0, 0, 0);
            aq[ct] = __builtin_amdgcn_mfma_f32_16x16x32_bf16(al, qh, aq[ct], 0, 0, 0);
            aq[ct] = __builtin_amdgcn_mfma_f32_16x16x32_bf16(ah, ql, aq[ct], 0, 0, 0);
            ak[ct] = __builtin_amdgcn_mfma_f32_16x16x32_bf16(ah, kh, ak[ct], 0, 0, 0);
            ak[ct] = __builtin_amdgcn_mfma_f32_16x16x32_bf16(al, kh, ak[ct], 0, 0, 0);
            ak[ct] = __builtin_amdgcn_mfma_f32_16x16x32_bf16(ah, kl, ak[ct], 0, 0, 0);
            av_[ct] = __builtin_amdgcn_mfma_f32_16x16x32_bf16(ah, vh, av_[ct], 0, 0, 0);
            av_[ct] = __builtin_amdgcn_mfma_f32_16x16x32_bf16(al, vh, av_[ct], 0, 0, 0);
            av_[ct] = __builtin_amdgcn_mfma_f32_16x16x32_bf16(ah, vl, av_[ct], 0, 0, 0);
        }
    }
    int orow0 = blockIdx.x * 64 + w * 16 + g * 4;
    #pragma unroll
    for (int ct = 0; ct < 4; ++ct) {
        int col = ct * 16 + m;
        #pragma unroll
        for (int r = 0; r < 4; ++r) {
            int row = orow0 + r;
            if (row < n) {
                q[(size_t)row * HH + col] = aq[ct][r];
                k[(size_t)row * HH + col] = ak[ct][r];
                v[(size_t)row * HH + col] = av_[ct][r];
            }
        }
    }
}

// ---------------- GAT edge phase: one wave/node, 16 lanes/edge, single gather pass --
template<bool LAST>
__global__ __launch_bounds__(256) void k_edge(
        const float* __restrict__ q, const float* __restrict__ karr,
        const float* __restrict__ varr,
        const int* __restrict__ rowptr, const int* __restrict__ eid,
        const int* __restrict__ esrc,
        float* __restrict__ ecsr,
        float* __restrict__ attn_out,
        float* __restrict__ hout,
        float* __restrict__ signals,
        const float* __restrict__ Wsig, const float* __restrict__ bsig,
        int n) {
    int node = blockIdx.x * 4 + (threadIdx.x >> 6);
    if (node >= n) return;
    int lane = threadIdx.x & 63;
    int li = lane & 15, g = lane >> 4;
    int start = rowptr[node], end = rowptr[node + 1];
    int deg = end - start;
    float4 qv = *reinterpret_cast<const float4*>(q + (size_t)node * HH + li * 4);
    int p0 = start + lane;
    int el = (p0 < end) ? esrc[p0] : 0;      // first 64 source indices in registers

    float4 acc = {0.f, 0.f, 0.f, 0.f};
    float s = 0.f;
    for (int c = 0; c < deg; c += 4) {
        int idx = c + g;
        bool valid = idx < deg;
        int sv;
        if (c < 64) sv = __shfl(el, idx);                 // wave-uniform branch
        else        sv = valid ? esrc[start + idx] : 0;
        const float4 kv = *reinterpret_cast<const float4*>(karr + (size_t)sv * HH + li * 4);
        const float4 vv = *reinterpret_cast<const float4*>(varr + (size_t)sv * HH + li * 4);
        float d = qv.x * kv.x + qv.y * kv.y + qv.z * kv.z + qv.w * kv.w;
        d += __shfl_xor(d, 1);
        d += __shfl_xor(d, 2);
        d += __shfl_xor(d, 4);
        d += __shfl_xor(d, 8);
        float e = valid ? __expf(fmaxf(d * 0.125f, 0.f)) : 0.f;
        s += e;
        if (valid && li == 0) ecsr[start + idx] = e;
        acc.x = fmaf(e, vv.x, acc.x);
        acc.y = fmaf(e, vv.y, acc.y);
        acc.z = fmaf(e, vv.z, acc.z);
        acc.w = fmaf(e, vv.w, acc.w);
    }
    // combine the 4 groups
    s += __shfl_xor(s, 16); s += __shfl_xor(s, 32);
    acc.x += __shfl_xor(acc.x, 16); acc.x += __shfl_xor(acc.x, 32);
    acc.y += __shfl_xor(acc.y, 16); acc.y += __shfl_xor(acc.y, 32);
    acc.z += __shfl_xor(acc.z, 16); acc.z += __shfl_xor(acc.z, 32);
    acc.w += __shfl_xor(acc.w, 16); acc.w += __shfl_xor(acc.w, 32);
    float inv = 1.0f / (s + 1e-16f);

    if (!LAST) {
        if (g == 0) {
            float4 o;
            o.x = gelu_f(acc.x * inv);
            o.y = gelu_f(acc.y * inv);
            o.z = gelu_f(acc.z * inv);
            o.w = gelu_f(acc.w * inv);
            *reinterpret_cast<float4*>(hout + (size_t)node * HH + li * 4) = o;
        }
    } else {
        float4 w4 = *reinterpret_cast<const float4*>(Wsig + li * 4);
        float t = (acc.x * w4.x + acc.y * w4.y + acc.z * w4.z + acc.w * w4.w) * inv;
        t += __shfl_xor(t, 1);
        t += __shfl_xor(t, 2);
        t += __shfl_xor(t, 4);
        t += __shfl_xor(t, 8);
        if (lane == 0) signals[node] = t + bsig[0];
    }
    // attention coefficients in original edge order
    for (int p = p0; p < end; p += 64)
        attn_out[eid[p]] = ecsr[p] * inv;
}

extern "C" void kernel_launch(void* const* d_in, const int* in_sizes, int n_in,
                              void* d_out, int out_size, void* d_ws, size_t ws_size,
                              hipStream_t stream) {
    const float* x   = (const float*)d_in[0];
    const int*   ei  = (const int*)  d_in[1];
    const float* Wp  = (const float*)d_in[2];
    const float* bp  = (const float*)d_in[3];
    const float* Wq1 = (const float*)d_in[4];
    const float* Wk1 = (const float*)d_in[5];
    const float* Wv1 = (const float*)d_in[6];
    const float* Wq2 = (const float*)d_in[7];
    const float* Wk2 = (const float*)d_in[8];
    const float* Wv2 = (const float*)d_in[9];
    const float* Wsg = (const float*)d_in[10];
    const float* bsg = (const float*)d_in[11];

    const int N = in_sizes[0] / FF;
    const int E = in_sizes[1] / 2;
    const int* src = ei;
    const int* dst = ei + E;

    char* ws = (char*)d_ws;
    size_t off = 0;
    auto alloc = [&](size_t bytes) -> void* {
        void* p = ws + off;
        off += (bytes + 255) & ~(size_t)255;
        return p;
    };
    float* q     = (float*)alloc((size_t)N * HH * 4);
    float* k     = (float*)alloc((size_t)N * HH * 4);
    float* v     = (float*)alloc((size_t)N * HH * 4);
    float* h     = (float*)alloc((size_t)N * HH * 4);
    float* ecsr  = (float*)alloc((size_t)E * 4);
    int* eid     = (int*)alloc((size_t)E * 4);
    int* esrc    = (int*)alloc((size_t)E * 4);
    int* degcur  = (int*)alloc((size_t)2 * N * 4);
    int* deg     = degcur;
    int* cursor  = degcur + N;
    int* rowptr  = (int*)alloc((size_t)(N + 1) * 4);
    int* bsums   = (int*)alloc(256 * 4);
    int* boffs   = (int*)alloc(256 * 4);
    short* wf    = (short*)alloc((size_t)81920 * 2);   // W fragment tables

    float* out     = (float*)d_out;
    float* signals = out;
    float* attn1   = out + N;
    float* attn2   = out + N + E;

    // W fragment prep (independent of CSR)
    k_wprep<<<64, 256, 0, stream>>>(Wp, Wq1, Wk1, Wv1, Wq2, Wk2, Wv2, wf);

    // CSR build
    hipMemsetAsync(degcur, 0, (size_t)2 * N * 4, stream);
    k_degree<<<(E + 255) / 256, 256, 0, stream>>>(dst, deg, E);
    int nb = (N + 1023) / 1024;
    k_scan1<<<nb, 256, 0, stream>>>(deg, rowptr, bsums, N);
    k_scan2<<<1, 256, 0, stream>>>(bsums, boffs, nb);
    k_scan3<<<(N + 1 + 255) / 256, 256, 0, stream>>>(rowptr, boffs, N, E);
    k_fill<<<(E + 255) / 256, 256, 0, stream>>>(src, dst, rowptr, cursor, eid, esrc, E);

    // GEMM grids: 64 rows/block (4 waves x 16 rows)
    int gemmBlocks = (N + 63) / 64;

    // layer 0: projection + gelu
    k_proj<<<gemmBlocks, 256, 0, stream>>>(x, wf, bp, h, N);

    const short* wfbase = wf + 32768;
    // layer 1
    k_qkv<<<gemmBlocks, 256, 0, stream>>>(h, wfbase, wfbase + 8192, wfbase + 16384,
            q, k, v, N);
    k_edge<false><<<(N + 3) / 4, 256, 0, stream>>>(q, k, v, rowptr, eid, esrc,
            ecsr, attn1, h, nullptr, nullptr, nullptr, N);

    // layer 2 (+ fused signal head)
    k_qkv<<<gemmBlocks, 256, 0, stream>>>(h, wfbase + 24576, wfbase + 32768, wfbase + 40960,
            q, k, v, N);
    k_edge<true><<<(N + 3) / 4, 256, 0, stream>>>(q, k, v, rowptr, eid, esrc,
            ecsr, attn2, nullptr, signals, Wsg, bsg, N);
}

// Round 5
// 462.994 us; speedup vs baseline: 2.2566x; 1.2073x over previous
//
#include <hip/hip_runtime.h>
#include <math.h>

#define FF 256
#define HH 64

typedef __attribute__((ext_vector_type(8))) short short8;
typedef __attribute__((ext_vector_type(8))) unsigned short ushort8;
typedef __attribute__((ext_vector_type(4))) float f32x4;

__device__ __forceinline__ float gelu_f(float x) {
    return 0.5f * x * (1.0f + erff(x * 0.70710678118654752f));
}

__device__ __forceinline__ unsigned short bf16rne(float f) {
    unsigned u = __float_as_uint(f);
    unsigned r = u + 0x7FFFu + ((u >> 16) & 1u);
    return (unsigned short)(r >> 16);
}
__device__ __forceinline__ float bf16tof(unsigned short s) {
    return __uint_as_float(((unsigned)s) << 16);
}

// split f into bf16 hi + bf16 lo (RNE)
__device__ __forceinline__ void bf16split(float f, short& hi, short& lo) {
    unsigned u = __float_as_uint(f);
    unsigned r = u + 0x7FFFu + ((u >> 16) & 1u);
    hi = (short)(r >> 16);
    float fh = __uint_as_float(r & 0xFFFF0000u);
    float fl = f - fh;
    unsigned u2 = __float_as_uint(fl);
    unsigned r2 = u2 + 0x7FFFu + ((u2 >> 16) & 1u);
    lo = (short)(r2 >> 16);
}

// ---- W fragment tables in workspace (bf16 hi/lo, fragment-ordered) ----
__global__ __launch_bounds__(256) void k_wprep(
        const float* __restrict__ Wp,
        const float* __restrict__ Wq1, const float* __restrict__ Wk1, const float* __restrict__ Wv1,
        const float* __restrict__ Wq2, const float* __restrict__ Wk2, const float* __restrict__ Wv2,
        short* __restrict__ wf) {
    int total = 16384 + 6 * 4096;
    for (int gid = blockIdx.x * 256 + threadIdx.x; gid < total; gid += gridDim.x * 256) {
        const float* W;
        int fid, hibase, lobase;
        if (gid < 16384) {
            W = Wp; fid = gid; hibase = 0; lobase = 16384;
        } else {
            int t = gid - 16384;
            int m = t >> 12;
            fid = t & 4095;
            switch (m) {
                case 0: W = Wq1; break;
                case 1: W = Wk1; break;
                case 2: W = Wv1; break;
                case 3: W = Wq2; break;
                case 4: W = Wk2; break;
                default: W = Wv2; break;
            }
            hibase = 32768 + m * 8192;
            lobase = hibase + 4096;
        }
        int j    = fid & 7;
        int lane = (fid >> 3) & 63;
        int ct   = (fid >> 9) & 3;
        int s    = fid >> 11;
        int k    = s * 32 + (lane >> 4) * 8 + j;
        int col  = ct * 16 + (lane & 15);
        short hi, lo;
        bf16split(W[k * HH + col], hi, lo);
        wf[hibase + fid] = hi;
        wf[lobase + fid] = lo;
    }
}

// ---------------- CSR build ----------------
__global__ __launch_bounds__(256) void k_degree(const int* __restrict__ dst,
        int* __restrict__ deg, int E) {
    int e = blockIdx.x * 256 + threadIdx.x;
    if (e < E) atomicAdd(&deg[dst[e]], 1);
}

__global__ __launch_bounds__(256) void k_scan1(const int* __restrict__ deg,
        int* __restrict__ out, int* __restrict__ bsums, int n) {
    __shared__ int lds[256];
    int t = threadIdx.x;
    int base = blockIdx.x * 1024 + t * 4;
    int v0 = (base     < n) ? deg[base]     : 0;
    int v1 = (base + 1 < n) ? deg[base + 1] : 0;
    int v2 = (base + 2 < n) ? deg[base + 2] : 0;
    int v3 = (base + 3 < n) ? deg[base + 3] : 0;
    int s = v0 + v1 + v2 + v3;
    int val = s;
    lds[t] = val;
    __syncthreads();
    #pragma unroll
    for (int off = 1; off < 256; off <<= 1) {
        int tmp = (t >= off) ? lds[t - off] : 0;
        __syncthreads();
        val += tmp;
        lds[t] = val;
        __syncthreads();
    }
    if (t == 255) bsums[blockIdx.x] = val;
    int excl = val - s;
    if (base     < n) out[base]     = excl;
    if (base + 1 < n) out[base + 1] = excl + v0;
    if (base + 2 < n) out[base + 2] = excl + v0 + v1;
    if (base + 3 < n) out[base + 3] = excl + v0 + v1 + v2;
}

__global__ __launch_bounds__(256) void k_scan2(const int* __restrict__ bsums,
        int* __restrict__ boffs, int nb) {
    __shared__ int lds[256];
    int t = threadIdx.x;
    int s = (t < nb) ? bsums[t] : 0;
    int val = s;
    lds[t] = val;
    __syncthreads();
    #pragma unroll
    for (int off = 1; off < 256; off <<= 1) {
        int tmp = (t >= off) ? lds[t - off] : 0;
        __syncthreads();
        val += tmp;
        lds[t] = val;
        __syncthreads();
    }
    if (t < nb) boffs[t] = val - s;
}

__global__ __launch_bounds__(256) void k_scan3(int* __restrict__ rowptr,
        const int* __restrict__ boffs, int n, int E) {
    int i = blockIdx.x * 256 + threadIdx.x;
    if (i < n) rowptr[i] += boffs[i >> 10];
    if (i == n) rowptr[n] = E;
}

__global__ __launch_bounds__(256) void k_fill(const int* __restrict__ src,
        const int* __restrict__ dst, const int* __restrict__ rowptr,
        int* __restrict__ cursor, int* __restrict__ eid, int* __restrict__ esrc, int E) {
    int e = blockIdx.x * 256 + threadIdx.x;
    if (e < E) {
        int d = dst[e];
        int pos = rowptr[d] + atomicAdd(&cursor[d], 1);
        eid[pos]  = e;
        esrc[pos] = src[e];
    }
}

// ---------------- proj GEMM + gelu via MFMA (split-bf16, 3 terms) ----------------
__global__ __launch_bounds__(256) void k_proj(const float* __restrict__ x,
        const short* __restrict__ wf, const float* __restrict__ b,
        float* __restrict__ h, int n) {
    int lane = threadIdx.x & 63;
    int w    = threadIdx.x >> 6;
    int m    = lane & 15, g = lane >> 4;
    int rowc = min(blockIdx.x * 64 + w * 16 + m, n - 1);
    const float* xrow = x + (size_t)rowc * FF + g * 8;
    const short* wlo = wf + 16384;
    f32x4 acc[4];
    #pragma unroll
    for (int ct = 0; ct < 4; ++ct) acc[ct] = (f32x4){0.f, 0.f, 0.f, 0.f};
    #pragma unroll
    for (int s = 0; s < 8; ++s) {
        float4 a0 = *reinterpret_cast<const float4*>(xrow + s * 32);
        float4 a1 = *reinterpret_cast<const float4*>(xrow + s * 32 + 4);
        float av[8] = {a0.x, a0.y, a0.z, a0.w, a1.x, a1.y, a1.z, a1.w};
        short8 ah, al;
        #pragma unroll
        for (int j = 0; j < 8; ++j) { short hi, lo; bf16split(av[j], hi, lo); ah[j] = hi; al[j] = lo; }
        #pragma unroll
        for (int ct = 0; ct < 4; ++ct) {
            int fo = ((s * 4 + ct) * 64 + lane) * 8;
            short8 bh = *reinterpret_cast<const short8*>(wf + fo);
            short8 bl = *reinterpret_cast<const short8*>(wlo + fo);
            acc[ct] = __builtin_amdgcn_mfma_f32_16x16x32_bf16(ah, bh, acc[ct], 0, 0, 0);
            acc[ct] = __builtin_amdgcn_mfma_f32_16x16x32_bf16(al, bh, acc[ct], 0, 0, 0);
            acc[ct] = __builtin_amdgcn_mfma_f32_16x16x32_bf16(ah, bl, acc[ct], 0, 0, 0);
        }
    }
    int orow0 = blockIdx.x * 64 + w * 16 + g * 4;
    #pragma unroll
    for (int ct = 0; ct < 4; ++ct) {
        int col = ct * 16 + m;
        float bias = b[col];
        #pragma unroll
        for (int r = 0; r < 4; ++r) {
            int row = orow0 + r;
            if (row < n) h[(size_t)row * HH + col] = gelu_f(acc[ct][r] + bias);
        }
    }
}

// ---------------- fused QKV GEMM via MFMA; k,v written as bf16 ----------------
__global__ __launch_bounds__(256) void k_qkv(const float* __restrict__ hsrc,
        const short* __restrict__ wfq, const short* __restrict__ wfk, const short* __restrict__ wfv,
        float* __restrict__ q, unsigned short* __restrict__ kb, unsigned short* __restrict__ vb, int n) {
    int lane = threadIdx.x & 63;
    int w    = threadIdx.x >> 6;
    int m    = lane & 15, g = lane >> 4;
    int rowc = min(blockIdx.x * 64 + w * 16 + m, n - 1);
    const float* hrow = hsrc + (size_t)rowc * HH + g * 8;
    f32x4 aq[4], ak[4], av_[4];
    #pragma unroll
    for (int ct = 0; ct < 4; ++ct) {
        aq[ct] = (f32x4){0.f, 0.f, 0.f, 0.f};
        ak[ct] = (f32x4){0.f, 0.f, 0.f, 0.f};
        av_[ct] = (f32x4){0.f, 0.f, 0.f, 0.f};
    }
    #pragma unroll
    for (int s = 0; s < 2; ++s) {
        float4 a0 = *reinterpret_cast<const float4*>(hrow + s * 32);
        float4 a1 = *reinterpret_cast<const float4*>(hrow + s * 32 + 4);
        float avv[8] = {a0.x, a0.y, a0.z, a0.w, a1.x, a1.y, a1.z, a1.w};
        short8 ah, al;
        #pragma unroll
        for (int j = 0; j < 8; ++j) { short hi, lo; bf16split(avv[j], hi, lo); ah[j] = hi; al[j] = lo; }
        #pragma unroll
        for (int ct = 0; ct < 4; ++ct) {
            int fo = ((s * 4 + ct) * 64 + lane) * 8;
            short8 qh = *reinterpret_cast<const short8*>(wfq + fo);
            short8 ql = *reinterpret_cast<const short8*>(wfq + 4096 + fo);
            short8 kh = *reinterpret_cast<const short8*>(wfk + fo);
            short8 kl = *reinterpret_cast<const short8*>(wfk + 4096 + fo);
            short8 vh = *reinterpret_cast<const short8*>(wfv + fo);
            short8 vl = *reinterpret_cast<const short8*>(wfv + 4096 + fo);
            aq[ct] = __builtin_amdgcn_mfma_f32_16x16x32_bf16(ah, qh, aq[ct], 0, 0, 0);
            aq[ct] = __builtin_amdgcn_mfma_f32_16x16x32_bf16(al, qh, aq[ct], 0, 0, 0);
            aq[ct] = __builtin_amdgcn_mfma_f32_16x16x32_bf16(ah, ql, aq[ct], 0, 0, 0);
            ak[ct] = __builtin_amdgcn_mfma_f32_16x16x32_bf16(ah, kh, ak[ct], 0, 0, 0);
            ak[ct] = __builtin_amdgcn_mfma_f32_16x16x32_bf16(al, kh, ak[ct], 0, 0, 0);
            ak[ct] = __builtin_amdgcn_mfma_f32_16x16x32_bf16(ah, kl, ak[ct], 0, 0, 0);
            av_[ct] = __builtin_amdgcn_mfma_f32_16x16x32_bf16(ah, vh, av_[ct], 0, 0, 0);
            av_[ct] = __builtin_amdgcn_mfma_f32_16x16x32_bf16(al, vh, av_[ct], 0, 0, 0);
            av_[ct] = __builtin_amdgcn_mfma_f32_16x16x32_bf16(ah, vl, av_[ct], 0, 0, 0);
        }
    }
    int orow0 = blockIdx.x * 64 + w * 16 + g * 4;
    #pragma unroll
    for (int ct = 0; ct < 4; ++ct) {
        int col = ct * 16 + m;
        #pragma unroll
        for (int r = 0; r < 4; ++r) {
            int row = orow0 + r;
            if (row < n) {
                q[(size_t)row * HH + col]  = aq[ct][r];
                kb[(size_t)row * HH + col] = bf16rne(ak[ct][r]);
                vb[(size_t)row * HH + col] = bf16rne(av_[ct][r]);
            }
        }
    }
}

// ---------------- GAT edge phase: one wave/node, 8 lanes/edge, bf16 gathers ------
template<bool LAST>
__global__ __launch_bounds__(256) void k_edge(
        const float* __restrict__ q, const unsigned short* __restrict__ karr,
        const unsigned short* __restrict__ varr,
        const int* __restrict__ rowptr, const int* __restrict__ eid,
        const int* __restrict__ esrc,
        float* __restrict__ ecsr,
        float* __restrict__ attn_out,
        float* __restrict__ hout,
        float* __restrict__ signals,
        const float* __restrict__ Wsig, const float* __restrict__ bsig,
        int n) {
    int node = blockIdx.x * 4 + (threadIdx.x >> 6);
    if (node >= n) return;
    int lane = threadIdx.x & 63;
    int li = lane & 7, g = lane >> 3;
    int start = rowptr[node], end = rowptr[node + 1];
    int deg = end - start;
    float qf[8];
    {
        float4 q0 = *reinterpret_cast<const float4*>(q + (size_t)node * HH + li * 8);
        float4 q1 = *reinterpret_cast<const float4*>(q + (size_t)node * HH + li * 8 + 4);
        qf[0] = q0.x; qf[1] = q0.y; qf[2] = q0.z; qf[3] = q0.w;
        qf[4] = q1.x; qf[5] = q1.y; qf[6] = q1.z; qf[7] = q1.w;
    }
    int p0 = start + lane;
    int el = (p0 < end) ? esrc[p0] : 0;   // first 64 source indices in registers

    float acc[8] = {0.f, 0.f, 0.f, 0.f, 0.f, 0.f, 0.f, 0.f};
    float s = 0.f;
    for (int c = 0; c < deg; c += 8) {
        int idx = c + g;
        bool valid = idx < deg;
        int sv;
        if (c < 64) sv = __shfl(el, idx);                 // wave-uniform branch
        else        sv = valid ? esrc[start + idx] : 0;
        ushort8 kv = *reinterpret_cast<const ushort8*>(karr + (size_t)sv * HH + li * 8);
        ushort8 vv = *reinterpret_cast<const ushort8*>(varr + (size_t)sv * HH + li * 8);
        float d = 0.f;
        #pragma unroll
        for (int j = 0; j < 8; ++j) d = fmaf(qf[j], bf16tof(kv[j]), d);
        d += __shfl_xor(d, 1);
        d += __shfl_xor(d, 2);
        d += __shfl_xor(d, 4);
        float e = valid ? __expf(fmaxf(d * 0.125f, 0.f)) : 0.f;
        s += e;
        if (valid && li == 0) ecsr[start + idx] = e;
        #pragma unroll
        for (int j = 0; j < 8; ++j) acc[j] = fmaf(e, bf16tof(vv[j]), acc[j]);
    }
    // combine the 8 groups
    #pragma unroll
    for (int off = 8; off < 64; off <<= 1) {
        s += __shfl_xor(s, off);
        #pragma unroll
        for (int j = 0; j < 8; ++j) acc[j] += __shfl_xor(acc[j], off);
    }
    float inv = 1.0f / (s + 1e-16f);

    if (!LAST) {
        if (g == 0) {
            float4 o0, o1;
            o0.x = gelu_f(acc[0] * inv); o0.y = gelu_f(acc[1] * inv);
            o0.z = gelu_f(acc[2] * inv); o0.w = gelu_f(acc[3] * inv);
            o1.x = gelu_f(acc[4] * inv); o1.y = gelu_f(acc[5] * inv);
            o1.z = gelu_f(acc[6] * inv); o1.w = gelu_f(acc[7] * inv);
            *reinterpret_cast<float4*>(hout + (size_t)node * HH + li * 8)     = o0;
            *reinterpret_cast<float4*>(hout + (size_t)node * HH + li * 8 + 4) = o1;
        }
    } else {
        float4 w0 = *reinterpret_cast<const float4*>(Wsig + li * 8);
        float4 w1 = *reinterpret_cast<const float4*>(Wsig + li * 8 + 4);
        float t = acc[0] * w0.x + acc[1] * w0.y + acc[2] * w0.z + acc[3] * w0.w
                + acc[4] * w1.x + acc[5] * w1.y + acc[6] * w1.z + acc[7] * w1.w;
        t *= inv;
        t += __shfl_xor(t, 1);
        t += __shfl_xor(t, 2);
        t += __shfl_xor(t, 4);
        if (lane == 0) signals[node] = t + bsig[0];
    }
    // attention coefficients in original edge order
    for (int p = p0; p < end; p += 64)
        attn_out[eid[p]] = ecsr[p] * inv;
}

extern "C" void kernel_launch(void* const* d_in, const int* in_sizes, int n_in,
                              void* d_out, int out_size, void* d_ws, size_t ws_size,
                              hipStream_t stream) {
    const float* x   = (const float*)d_in[0];
    const int*   ei  = (const int*)  d_in[1];
    const float* Wp  = (const float*)d_in[2];
    const float* bp  = (const float*)d_in[3];
    const float* Wq1 = (const float*)d_in[4];
    const float* Wk1 = (const float*)d_in[5];
    const float* Wv1 = (const float*)d_in[6];
    const float* Wq2 = (const float*)d_in[7];
    const float* Wk2 = (const float*)d_in[8];
    const float* Wv2 = (const float*)d_in[9];
    const float* Wsg = (const float*)d_in[10];
    const float* bsg = (const float*)d_in[11];

    const int N = in_sizes[0] / FF;
    const int E = in_sizes[1] / 2;
    const int* src = ei;
    const int* dst = ei + E;

    char* ws = (char*)d_ws;
    size_t off = 0;
    auto alloc = [&](size_t bytes) -> void* {
        void* p = ws + off;
        off += (bytes + 255) & ~(size_t)255;
        return p;
    };
    float* q          = (float*)alloc((size_t)N * HH * 4);
    unsigned short* kb = (unsigned short*)alloc((size_t)N * HH * 2);
    unsigned short* vb = (unsigned short*)alloc((size_t)N * HH * 2);
    float* h          = (float*)alloc((size_t)N * HH * 4);
    float* ecsr       = (float*)alloc((size_t)E * 4);
    int* eid          = (int*)alloc((size_t)E * 4);
    int* esrc         = (int*)alloc((size_t)E * 4);
    int* degcur       = (int*)alloc((size_t)2 * N * 4);
    int* deg          = degcur;
    int* cursor       = degcur + N;
    int* rowptr       = (int*)alloc((size_t)(N + 1) * 4);
    int* bsums        = (int*)alloc(256 * 4);
    int* boffs        = (int*)alloc(256 * 4);
    short* wf         = (short*)alloc((size_t)81920 * 2);   // W fragment tables

    float* out     = (float*)d_out;
    float* signals = out;
    float* attn1   = out + N;
    float* attn2   = out + N + E;

    // W fragment prep (independent of CSR)
    k_wprep<<<64, 256, 0, stream>>>(Wp, Wq1, Wk1, Wv1, Wq2, Wk2, Wv2, wf);

    // CSR build
    hipMemsetAsync(degcur, 0, (size_t)2 * N * 4, stream);
    k_degree<<<(E + 255) / 256, 256, 0, stream>>>(dst, deg, E);
    int nb = (N + 1023) / 1024;
    k_scan1<<<nb, 256, 0, stream>>>(deg, rowptr, bsums, N);
    k_scan2<<<1, 256, 0, stream>>>(bsums, boffs, nb);
    k_scan3<<<(N + 1 + 255) / 256, 256, 0, stream>>>(rowptr, boffs, N, E);
    k_fill<<<(E + 255) / 256, 256, 0, stream>>>(src, dst, rowptr, cursor, eid, esrc, E);

    // GEMM grids: 64 rows/block (4 waves x 16 rows)
    int gemmBlocks = (N + 63) / 64;

    // layer 0: projection + gelu
    k_proj<<<gemmBlocks, 256, 0, stream>>>(x, wf, bp, h, N);

    const short* wfbase = wf + 32768;
    // layer 1
    k_qkv<<<gemmBlocks, 256, 0, stream>>>(h, wfbase, wfbase + 8192, wfbase + 16384,
            q, kb, vb, N);
    k_edge<false><<<(N + 3) / 4, 256, 0, stream>>>(q, kb, vb, rowptr, eid, esrc,
            ecsr, attn1, h, nullptr, nullptr, nullptr, N);

    // layer 2 (+ fused signal head)
    k_qkv<<<gemmBlocks, 256, 0, stream>>>(h, wfbase + 24576, wfbase + 32768, wfbase + 40960,
            q, kb, vb, N);
    k_edge<true><<<(N + 3) / 4, 256, 0, stream>>>(q, kb, vb, rowptr, eid, esrc,
            ecsr, attn2, nullptr, signals, Wsg, bsg, N);
}